// Round 15
// baseline (281.491 us; speedup 1.0000x reference)
//
#include <hip/hip_runtime.h>
#include <hip/hip_cooperative_groups.h>

namespace cg = cooperative_groups;

#define BB 16
#define TV 256
#define TS 32
#define DD 512

typedef float    floatx4  __attribute__((ext_vector_type(4)));
typedef short    short8   __attribute__((ext_vector_type(8)));
typedef unsigned short ushort8 __attribute__((ext_vector_type(8)));

#define TANH_SCALE 2.885390082f   // 2*log2(e): tanh(y)=1-2/(exp2(2y*log2e)+1)

static __device__ __forceinline__ unsigned short f2bf(float f) {
    unsigned int u = __float_as_uint(f);
    u += 0x7FFFu + ((u >> 16) & 1u);   // RNE (inputs finite)
    return (unsigned short)(u >> 16);
}

// ===========================================================================
// FUSED cooperative kernel, grid 512 x 256 (2 blocks/CU — well under the
// co-residency limit; R14's grid=1024 was AT the limit and failed to launch).
// Phases: convert -> grid.sync -> GEMM(+exp epilogue) -> grid.sync -> tanh.
// ===========================================================================
__global__ __launch_bounds__(256, 2) void ta_fused(
    const float* __restrict__ video, const float* __restrict__ sent,
    const float* __restrict__ w1,    const float* __restrict__ w2,
    const float* __restrict__ b1,    const float* __restrict__ vmask,
    const float* __restrict__ smask, const float* __restrict__ wt,
    unsigned short* __restrict__ vb, unsigned short* __restrict__ sb,
    unsigned short* __restrict__ w1b, unsigned short* __restrict__ w2b,
    unsigned short* __restrict__ tmp1h, unsigned short* __restrict__ tmp2h,
    float* __restrict__ wsum_g,      float* __restrict__ out)
{
    __shared__ union {
        struct { unsigned short As[2][4096]; unsigned short Bs[2][4096]; } g; // 32 KB
        struct { unsigned int e2u[8192];                                      // 32 KB
                 unsigned short e1u[8 * 520];                                 // 8.1 KB
                 float part[512]; } c;                                        // 2 KB
    } sm;

    cg::grid_group grid = cg::this_grid();
    const int t   = threadIdx.x;
    const int bid = blockIdx.x;

    // ---------------- Phase A: convert f32 -> bf16 (grid-stride) ----------
    {
        const int NV = BB * TV * DD, NS = BB * TS * DD, NW = DD * DD;
        const int total8 = (NV + NS + 2 * NW) / 8;        // 360448 chunks
        for (int ch = bid * 256 + t; ch < total8; ch += 512 * 256) {
            const int base = ch * 8;
            const float* src; unsigned short* dst; int off;
            if      (base < NV)           { src = video; dst = vb;  off = base; }
            else if (base < NV + NS)      { src = sent;  dst = sb;  off = base - NV; }
            else if (base < NV + NS + NW) { src = w1;    dst = w1b; off = base - NV - NS; }
            else                          { src = w2;    dst = w2b; off = base - NV - NS - NW; }
            const float4 a = *(const float4*)(src + off);
            const float4 b = *(const float4*)(src + off + 4);
            ushort8 o;
            o[0] = f2bf(a.x); o[1] = f2bf(a.y); o[2] = f2bf(a.z); o[3] = f2bf(a.w);
            o[4] = f2bf(b.x); o[5] = f2bf(b.y); o[6] = f2bf(b.z); o[7] = f2bf(b.w);
            *(ushort8*)(dst + off) = o;
        }
        if (bid == 0 && t < 64) {
            float v = 0.f;
            for (int i = t; i < DD; i += 64) v += wt[i];
            for (int off = 32; off; off >>= 1) v += __shfl_down(v, off);
            if (t == 0) wsum_g[0] = v;
        }
    }
    __threadfence();
    grid.sync();

    // ---------------- Phase B: merged bf16-MFMA NT GEMM (576 tiles) --------
    for (int tb576 = bid; tb576 < 576; tb576 += 512) {
        const bool g2 = (tb576 >= 512);
        const int tb  = g2 ? tb576 - 512 : tb576;
        const unsigned short* __restrict__ A = g2 ? sb    : vb;
        const unsigned short* __restrict__ W = g2 ? w2b   : w1b;
        const float* __restrict__ rm         = g2 ? smask : vmask;
        const int m0 = (g2 ? (tb & 7)  : (tb & 63)) * 64;
        const int n0 = (g2 ? (tb >> 3) : (tb >> 6)) * 64;

        const int lane = t & 63;
        const int wid  = t >> 6;
        const int wm   = wid >> 1, wn = wid & 1;
        const int lr   = lane & 15, kg = lane >> 4;

        const int r0 = t >> 3,          g0c = (t & 7) ^ (r0 & 7);
        const int r1 = (t + 256) >> 3,  g1c = (t & 7) ^ (r1 & 7);
        const unsigned short* a0p = A + (size_t)(m0 + r0) * DD + g0c * 8;
        const unsigned short* a1p = A + (size_t)(m0 + r1) * DD + g1c * 8;
        const unsigned short* w0p = W + (size_t)(n0 + r0) * DD + g0c * 8;
        const unsigned short* w1p = W + (size_t)(n0 + r1) * DD + g1c * 8;
        const int l0 = t * 8;
        const int l1 = (t + 256) * 8;

#define TA_STAGE(buf, koff) do {                                               \
    __builtin_amdgcn_global_load_lds(                                          \
        (const __attribute__((address_space(1))) void*)(a0p + (koff)),         \
        (__attribute__((address_space(3))) void*)&sm.g.As[buf][l0], 16, 0, 0); \
    __builtin_amdgcn_global_load_lds(                                          \
        (const __attribute__((address_space(1))) void*)(a1p + (koff)),         \
        (__attribute__((address_space(3))) void*)&sm.g.As[buf][l1], 16, 0, 0); \
    __builtin_amdgcn_global_load_lds(                                          \
        (const __attribute__((address_space(1))) void*)(w0p + (koff)),         \
        (__attribute__((address_space(3))) void*)&sm.g.Bs[buf][l0], 16, 0, 0); \
    __builtin_amdgcn_global_load_lds(                                          \
        (const __attribute__((address_space(1))) void*)(w1p + (koff)),         \
        (__attribute__((address_space(3))) void*)&sm.g.Bs[buf][l1], 16, 0, 0); \
  } while (0)

        floatx4 acc[2][2] = {};

        const int ml0 = wm * 32 + lr, ml1 = ml0 + 16;
        const int nl0 = wn * 32 + lr, nl1 = nl0 + 16;
        const int sa0 = ml0 * 64, sa1 = ml1 * 64;
        const int sb0 = nl0 * 64, sb1 = nl1 * 64;
        const int xa = ml0 & 7, xb = nl0 & 7;

        TA_STAGE(0, 0);
        __syncthreads();

        int cur = 0;
        for (int step = 0; step < 8; ++step) {
            if (step < 7) TA_STAGE(cur ^ 1, (step + 1) * 64);
#pragma unroll
            for (int kk = 0; kk < 2; ++kk) {
                const int kc = kk * 4 + kg;
                short8 a0 = *(const short8*)&sm.g.As[cur][sa0 + ((kc ^ xa) << 3)];
                short8 a1 = *(const short8*)&sm.g.As[cur][sa1 + ((kc ^ xa) << 3)];
                short8 b0 = *(const short8*)&sm.g.Bs[cur][sb0 + ((kc ^ xb) << 3)];
                short8 b1 = *(const short8*)&sm.g.Bs[cur][sb1 + ((kc ^ xb) << 3)];
                acc[0][0] = __builtin_amdgcn_mfma_f32_16x16x32_bf16(a0, b0, acc[0][0], 0, 0, 0);
                acc[0][1] = __builtin_amdgcn_mfma_f32_16x16x32_bf16(a0, b1, acc[0][1], 0, 0, 0);
                acc[1][0] = __builtin_amdgcn_mfma_f32_16x16x32_bf16(a1, b0, acc[1][0], 0, 0, 0);
                acc[1][1] = __builtin_amdgcn_mfma_f32_16x16x32_bf16(a1, b1, acc[1][1], 0, 0, 0);
            }
            __syncthreads();
            cur ^= 1;
        }
#undef TA_STAGE

#pragma unroll
        for (int fm = 0; fm < 2; ++fm)
#pragma unroll
            for (int fn = 0; fn < 2; ++fn)
#pragma unroll
                for (int r = 0; r < 4; ++r) {
                    const int m = m0 + wm * 32 + fm * 16 + kg * 4 + r;
                    const int n = n0 + wn * 32 + fn * 16 + lr;
                    const float mk = rm[m] * TANH_SCALE;
                    float z = g2 ? (acc[fm][fn][r] * mk)
                                 : (acc[fm][fn][r] + b1[n]) * mk;
                    z = fminf(fmaxf(z, -30.f), 30.f);
                    const float e = __builtin_amdgcn_exp2f(z);
                    if (!g2) {
                        tmp1h[(size_t)m * DD + n] = f2bf(e);
                    } else {
                        const int bb = m >> 5, ss = m & 31;
                        tmp2h[(size_t)bb * 16384 + (size_t)(ss >> 4) * 8192
                              + (size_t)(n >> 1) * 32 + (ss & 15) * 2 + (n & 1)] = f2bf(e);
                    }
                }
    }
    __threadfence();
    grid.sync();

    // ---------------- Phase C: tanh reduction, 512 uniform tiles of 8 v ----
    {
        const int b  = bid >> 5;            // 16 batches x 32 v-tiles
        const int v0 = (bid & 31) << 3;

        // stage E2 32KB (8x16B/thread) + E1 8 rows (2x16B/thread); all dests
        // are wave-uniform-base + lane*16 (row = chunk>>6 is wave-uniform).
        const unsigned short* e2src = tmp2h + (size_t)b * 16384 + t * 8;
#pragma unroll
        for (int i = 0; i < 8; ++i) {
            __builtin_amdgcn_global_load_lds(
                (const __attribute__((address_space(1))) void*)(e2src + i * 2048),
                (__attribute__((address_space(3))) void*)&sm.c.e2u[t * 4 + i * 1024], 16, 0, 0);
        }
#pragma unroll
        for (int i = 0; i < 2; ++i) {
            const int chunk = t + 256 * i;             // 512 chunks = 8 rows
            const int row = chunk >> 6, col = (chunk & 63) * 8;
            __builtin_amdgcn_global_load_lds(
                (const __attribute__((address_space(1))) void*)
                    (tmp1h + (size_t)(b * TV + v0 + row) * DD + col),
                (__attribute__((address_space(3))) void*)&sm.c.e1u[row * 520 + col], 16, 0, 0);
        }
        __syncthreads();

        const int s  = t & 31;
        const int vi = (t >> 5) & 3;        // thread covers v rows vi, vi+4
        const int q  = t >> 7;              // 0..1, 256-d slice

        const unsigned short* __restrict__ e1lo = sm.c.e1u + vi * 520 + q * 256;
        const unsigned short* __restrict__ e1hi = sm.c.e1u + (vi + 4) * 520 + q * 256;
        const float* __restrict__ wtp = wt + q * 256;
        const int ubase = (s >> 4) * 4096 + q * 2048 + (s & 15);

        floatx4 alo = {0.f, 0.f, 0.f, 0.f};
        floatx4 ahi = {0.f, 0.f, 0.f, 0.f};
#pragma unroll 4
        for (int i = 0; i < 32; ++i) {
            const int ub = ubase + i * 64;
            const unsigned u0 = sm.c.e2u[ub];
            const unsigned u1 = sm.c.e2u[ub + 16];
            const unsigned u2 = sm.c.e2u[ub + 32];
            const unsigned u3 = sm.c.e2u[ub + 48];
            ushort8 l8 = *(const ushort8*)(e1lo + i * 8);   // half-wave broadcast
            ushort8 h8 = *(const ushort8*)(e1hi + i * 8);
            floatx4 wa = *(const floatx4*)(wtp + i * 8);
            floatx4 wb = *(const floatx4*)(wtp + i * 8 + 4);
            const float e2v[8] = {
                __uint_as_float(u0 << 16), __uint_as_float(u0 & 0xffff0000u),
                __uint_as_float(u1 << 16), __uint_as_float(u1 & 0xffff0000u),
                __uint_as_float(u2 << 16), __uint_as_float(u2 & 0xffff0000u),
                __uint_as_float(u3 << 16), __uint_as_float(u3 & 0xffff0000u)
            };
#pragma unroll
            for (int j = 0; j < 4; ++j) {
                const float xl = __uint_as_float((unsigned)l8[j] << 16);
                const float xh = __uint_as_float((unsigned)h8[j] << 16);
                const float rl = __builtin_amdgcn_rcpf(fmaf(xl, e2v[j], 1.f));
                const float rh = __builtin_amdgcn_rcpf(fmaf(xh, e2v[j], 1.f));
                alo[j] = fmaf(wa[j], rl, alo[j]);
                ahi[j] = fmaf(wa[j], rh, ahi[j]);
            }
#pragma unroll
            for (int j = 0; j < 4; ++j) {
                const float xl = __uint_as_float((unsigned)l8[j + 4] << 16);
                const float xh = __uint_as_float((unsigned)h8[j + 4] << 16);
                const float rl = __builtin_amdgcn_rcpf(fmaf(xl, e2v[j + 4], 1.f));
                const float rh = __builtin_amdgcn_rcpf(fmaf(xh, e2v[j + 4], 1.f));
                alo[j] = fmaf(wb[j], rl, alo[j]);
                ahi[j] = fmaf(wb[j], rh, ahi[j]);
            }
        }

        sm.c.part[(vi    ) * 64 + s * 2 + q] = (alo[0] + alo[1]) + (alo[2] + alo[3]);
        sm.c.part[(vi + 4) * 64 + s * 2 + q] = (ahi[0] + ahi[1]) + (ahi[2] + ahi[3]);
        __syncthreads();

        {   // 256 threads = 8v x 32s outputs
            const int vrow = t >> 5, s2 = t & 31;
            const float sum = sm.c.part[vrow * 64 + s2 * 2]
                            + sm.c.part[vrow * 64 + s2 * 2 + 1];
            const int v = v0 + vrow;
            const float pm = vmask[b * TV + v] * smask[b * TS + s2];
            out[((size_t)b * TV + v) * TS + s2] = pm * (wsum_g[0] - 2.f * sum);
        }
    }
}

// ===========================================================================
// FALLBACK path (R13, known-good 35.3us): three kernels, same buffer layouts.
// ===========================================================================
__global__ __launch_bounds__(256) void ta_convert(
    const float* __restrict__ video, const float* __restrict__ sent,
    const float* __restrict__ w1,    const float* __restrict__ w2,
    unsigned short* __restrict__ vb, unsigned short* __restrict__ sb,
    unsigned short* __restrict__ w1b, unsigned short* __restrict__ w2b)
{
    const int NV = BB * TV * DD, NS = BB * TS * DD, NW = DD * DD;
    const int base = (blockIdx.x * 256 + threadIdx.x) * 8;
    const float* src; unsigned short* dst; int off;
    if      (base < NV)           { src = video; dst = vb;  off = base; }
    else if (base < NV + NS)      { src = sent;  dst = sb;  off = base - NV; }
    else if (base < NV + NS + NW) { src = w1;    dst = w1b; off = base - NV - NS; }
    else                          { src = w2;    dst = w2b; off = base - NV - NS - NW; }
    const float4 a = *(const float4*)(src + off);
    const float4 b = *(const float4*)(src + off + 4);
    ushort8 o;
    o[0] = f2bf(a.x); o[1] = f2bf(a.y); o[2] = f2bf(a.z); o[3] = f2bf(a.w);
    o[4] = f2bf(b.x); o[5] = f2bf(b.y); o[6] = f2bf(b.z); o[7] = f2bf(b.w);
    *(ushort8*)(dst + off) = o;
}

__global__ __launch_bounds__(256) void ta_mfma_gemm(
    const unsigned short* __restrict__ vb, const unsigned short* __restrict__ w1b,
    const float* __restrict__ b1,          const float* __restrict__ vmask,
    unsigned short* __restrict__ tmp1h,
    const unsigned short* __restrict__ sb, const unsigned short* __restrict__ w2b,
    const float* __restrict__ smask,       unsigned short* __restrict__ tmp2h,
    const float* __restrict__ wt,          float* __restrict__ wsum)
{
    const int t = threadIdx.x;
    if (blockIdx.x == 0 && t < 64) {
        float v = 0.f;
        for (int i = t; i < DD; i += 64) v += wt[i];
        for (int off = 32; off; off >>= 1) v += __shfl_down(v, off);
        if (t == 0) wsum[0] = v;
    }
    const bool g2 = (blockIdx.x >= 512);
    const int bid = g2 ? (int)blockIdx.x - 512 : (int)blockIdx.x;
    const unsigned short* __restrict__ A = g2 ? sb    : vb;
    const unsigned short* __restrict__ W = g2 ? w2b   : w1b;
    const float* __restrict__ rm         = g2 ? smask : vmask;
    const int m0 = (g2 ? (bid & 7)  : (bid & 63)) * 64;
    const int n0 = (g2 ? (bid >> 3) : (bid >> 6)) * 64;

    __shared__ unsigned short As[2][4096];
    __shared__ unsigned short Bs[2][4096];

    const int lane = t & 63;
    const int wid  = t >> 6;
    const int wm   = wid >> 1, wn = wid & 1;
    const int lr   = lane & 15, kg = lane >> 4;

    const int r0 = t >> 3,          g0c = (t & 7) ^ (r0 & 7);
    const int r1 = (t + 256) >> 3,  g1c = (t & 7) ^ (r1 & 7);
    const unsigned short* a0p = A + (size_t)(m0 + r0) * DD + g0c * 8;
    const unsigned short* a1p = A + (size_t)(m0 + r1) * DD + g1c * 8;
    const unsigned short* w0p = W + (size_t)(n0 + r0) * DD + g0c * 8;
    const unsigned short* w1p = W + (size_t)(n0 + r1) * DD + g1c * 8;
    const int l0 = t * 8;
    const int l1 = (t + 256) * 8;

#define TA_STAGE2(buf, koff) do {                                              \
    __builtin_amdgcn_global_load_lds(                                          \
        (const __attribute__((address_space(1))) void*)(a0p + (koff)),         \
        (__attribute__((address_space(3))) void*)&As[buf][l0], 16, 0, 0);      \
    __builtin_amdgcn_global_load_lds(                                          \
        (const __attribute__((address_space(1))) void*)(a1p + (koff)),         \
        (__attribute__((address_space(3))) void*)&As[buf][l1], 16, 0, 0);      \
    __builtin_amdgcn_global_load_lds(                                          \
        (const __attribute__((address_space(1))) void*)(w0p + (koff)),         \
        (__attribute__((address_space(3))) void*)&Bs[buf][l0], 16, 0, 0);      \
    __builtin_amdgcn_global_load_lds(                                          \
        (const __attribute__((address_space(1))) void*)(w1p + (koff)),         \
        (__attribute__((address_space(3))) void*)&Bs[buf][l1], 16, 0, 0);      \
  } while (0)

    floatx4 acc[2][2] = {};
    const int ml0 = wm * 32 + lr, ml1 = ml0 + 16;
    const int nl0 = wn * 32 + lr, nl1 = nl0 + 16;
    const int sa0 = ml0 * 64, sa1 = ml1 * 64;
    const int sb0 = nl0 * 64, sb1 = nl1 * 64;
    const int xa = ml0 & 7, xb = nl0 & 7;

    TA_STAGE2(0, 0);
    __syncthreads();
    int cur = 0;
    for (int step = 0; step < 8; ++step) {
        if (step < 7) TA_STAGE2(cur ^ 1, (step + 1) * 64);
#pragma unroll
        for (int kk = 0; kk < 2; ++kk) {
            const int kc = kk * 4 + kg;
            short8 a0 = *(const short8*)&As[cur][sa0 + ((kc ^ xa) << 3)];
            short8 a1 = *(const short8*)&As[cur][sa1 + ((kc ^ xa) << 3)];
            short8 b0 = *(const short8*)&Bs[cur][sb0 + ((kc ^ xb) << 3)];
            short8 b1 = *(const short8*)&Bs[cur][sb1 + ((kc ^ xb) << 3)];
            acc[0][0] = __builtin_amdgcn_mfma_f32_16x16x32_bf16(a0, b0, acc[0][0], 0, 0, 0);
            acc[0][1] = __builtin_amdgcn_mfma_f32_16x16x32_bf16(a0, b1, acc[0][1], 0, 0, 0);
            acc[1][0] = __builtin_amdgcn_mfma_f32_16x16x32_bf16(a1, b0, acc[1][0], 0, 0, 0);
            acc[1][1] = __builtin_amdgcn_mfma_f32_16x16x32_bf16(a1, b1, acc[1][1], 0, 0, 0);
        }
        __syncthreads();
        cur ^= 1;
    }
#undef TA_STAGE2

#pragma unroll
    for (int fm = 0; fm < 2; ++fm)
#pragma unroll
        for (int fn = 0; fn < 2; ++fn)
#pragma unroll
            for (int r = 0; r < 4; ++r) {
                const int m = m0 + wm * 32 + fm * 16 + kg * 4 + r;
                const int n = n0 + wn * 32 + fn * 16 + lr;
                const float mk = rm[m] * TANH_SCALE;
                float z = g2 ? (acc[fm][fn][r] * mk)
                             : (acc[fm][fn][r] + b1[n]) * mk;
                z = fminf(fmaxf(z, -30.f), 30.f);
                const float e = __builtin_amdgcn_exp2f(z);
                if (!g2) {
                    tmp1h[(size_t)m * DD + n] = f2bf(e);
                } else {
                    const int bb = m >> 5, ss = m & 31;
                    tmp2h[(size_t)bb * 16384 + (size_t)(ss >> 4) * 8192
                          + (size_t)(n >> 1) * 32 + (ss & 15) * 2 + (n & 1)] = f2bf(e);
                }
            }
}

__global__ __launch_bounds__(256, 6) void ta_tanh_main(
    const unsigned short* __restrict__ tmp1h,
    const unsigned short* __restrict__ tmp2h,
    const float* __restrict__ wt,   const float* __restrict__ wsum,
    const float* __restrict__ vmask, const float* __restrict__ smask,
    float* __restrict__ out)
{
    __shared__ unsigned int   e2u[4096];
    __shared__ unsigned short e1u[4 * 520];
    __shared__ float part[512];

    const int t   = threadIdx.x;
    const int bid = blockIdx.x;
    const int b   = bid >> 7;
    const int vt  = (bid >> 1) & 63;
    const int sh  = bid & 1;
    const int v0  = vt << 2;

    const unsigned short* e2src = tmp2h + (size_t)b * 16384 + sh * 8192 + t * 8;
#pragma unroll
    for (int i = 0; i < 4; ++i) {
        __builtin_amdgcn_global_load_lds(
            (const __attribute__((address_space(1))) void*)(e2src + i * 2048),
            (__attribute__((address_space(3))) void*)&e2u[t * 4 + i * 1024], 16, 0, 0);
    }
    {
        const int row = t >> 6, col = (t & 63) * 8;
        __builtin_amdgcn_global_load_lds(
            (const __attribute__((address_space(1))) void*)
                (tmp1h + (size_t)(b * TV + v0 + row) * DD + col),
            (__attribute__((address_space(3))) void*)&e1u[row * 520 + col], 16, 0, 0);
    }
    __syncthreads();

    const int s  = t & 15;
    const int vi = (t >> 4) & 1;
    const int q  = t >> 5;

    const unsigned short* __restrict__ e1lo = e1u + vi * 520 + q * 64;
    const unsigned short* __restrict__ e1hi = e1u + (vi + 2) * 520 + q * 64;
    const float* __restrict__ wtp = wt + q * 64;
    const int ubase = q * 512 + s;

    floatx4 alo = {0.f, 0.f, 0.f, 0.f};
    floatx4 ahi = {0.f, 0.f, 0.f, 0.f};
#pragma unroll
    for (int i = 0; i < 8; ++i) {
        const int ub = ubase + i * 64;
        const unsigned u0 = e2u[ub];
        const unsigned u1 = e2u[ub + 16];
        const unsigned u2 = e2u[ub + 32];
        const unsigned u3 = e2u[ub + 48];
        ushort8 l8 = *(const ushort8*)(e1lo + i * 8);
        ushort8 h8 = *(const ushort8*)(e1hi + i * 8);
        floatx4 wa = *(const floatx4*)(wtp + i * 8);
        floatx4 wb = *(const floatx4*)(wtp + i * 8 + 4);
        const float e2v[8] = {
            __uint_as_float(u0 << 16), __uint_as_float(u0 & 0xffff0000u),
            __uint_as_float(u1 << 16), __uint_as_float(u1 & 0xffff0000u),
            __uint_as_float(u2 << 16), __uint_as_float(u2 & 0xffff0000u),
            __uint_as_float(u3 << 16), __uint_as_float(u3 & 0xffff0000u)
        };
#pragma unroll
        for (int j = 0; j < 4; ++j) {
            const float xl = __uint_as_float((unsigned)l8[j] << 16);
            const float xh = __uint_as_float((unsigned)h8[j] << 16);
            const float rl = __builtin_amdgcn_rcpf(fmaf(xl, e2v[j], 1.f));
            const float rh = __builtin_amdgcn_rcpf(fmaf(xh, e2v[j], 1.f));
            alo[j] = fmaf(wa[j], rl, alo[j]);
            ahi[j] = fmaf(wa[j], rh, ahi[j]);
        }
#pragma unroll
        for (int j = 0; j < 4; ++j) {
            const float xl = __uint_as_float((unsigned)l8[j + 4] << 16);
            const float xh = __uint_as_float((unsigned)h8[j + 4] << 16);
            const float rl = __builtin_amdgcn_rcpf(fmaf(xl, e2v[j + 4], 1.f));
            const float rh = __builtin_amdgcn_rcpf(fmaf(xh, e2v[j + 4], 1.f));
            alo[j] = fmaf(wb[j], rl, alo[j]);
            ahi[j] = fmaf(wb[j], rh, ahi[j]);
        }
    }

    part[(vi    ) * 128 + s * 8 + q] = (alo[0] + alo[1]) + (alo[2] + alo[3]);
    part[(vi + 2) * 128 + s * 8 + q] = (ahi[0] + ahi[1]) + (ahi[2] + ahi[3]);
    __syncthreads();

    if (t < 64) {
        const int vrow = t >> 4, s2 = t & 15;
        const floatx4 p0 = *(const floatx4*)&part[vrow * 128 + s2 * 8];
        const floatx4 p1 = *(const floatx4*)&part[vrow * 128 + s2 * 8 + 4];
        const float sum = ((p0[0] + p0[1]) + (p0[2] + p0[3]))
                        + ((p1[0] + p1[1]) + (p1[2] + p1[3]));
        const int v  = v0 + vrow;
        const int sg = sh * 16 + s2;
        const float pm = vmask[b * TV + v] * smask[b * TS + sg];
        out[((size_t)b * TV + v) * TS + sg] = pm * (wsum[0] - 2.f * sum);
    }
}

// ---------------------------------------------------------------------------
extern "C" void kernel_launch(void* const* d_in, const int* in_sizes, int n_in,
                              void* d_out, int out_size, void* d_ws, size_t ws_size,
                              hipStream_t stream)
{
    const float* video = (const float*)d_in[0];
    const float* vmask = (const float*)d_in[1];
    const float* sent  = (const float*)d_in[2];
    const float* smask = (const float*)d_in[3];
    const float* w1    = (const float*)d_in[4];
    const float* b1    = (const float*)d_in[5];
    const float* w2    = (const float*)d_in[6];
    const float* wt    = (const float*)d_in[7];
    float* out = (float*)d_out;

    const size_t NV = (size_t)BB * TV * DD, NS = (size_t)BB * TS * DD, NW = (size_t)DD * DD;

    unsigned short* tmp1h = (unsigned short*)d_ws;   // 4 MB bf16 (E1)
    unsigned short* tmp2h = tmp1h + NV;              // 512 KB bf16 (E2)
    unsigned short* vb    = tmp2h + NS;
    unsigned short* sb    = vb + NV;
    unsigned short* w1b   = sb + NS;
    unsigned short* w2b   = w1b + NW;
    float* wsum           = (float*)(w2b + NW);

    void* args[] = {
        (void*)&video, (void*)&sent, (void*)&w1, (void*)&w2,
        (void*)&b1, (void*)&vmask, (void*)&smask, (void*)&wt,
        (void*)&vb, (void*)&sb, (void*)&w1b, (void*)&w2b,
        (void*)&tmp1h, (void*)&tmp2h, (void*)&wsum, (void*)&out
    };
    hipError_t err = hipLaunchCooperativeKernel((void*)ta_fused, dim3(512),
                                                dim3(256), args, 0, stream);
    if (err != hipSuccess) {
        (void)hipGetLastError();   // clear sticky error, take fallback path
        const int total8 = (int)((NV + NS + 2 * NW) / 8);
        ta_convert<<<dim3(total8 / 256), dim3(256), 0, stream>>>(
            video, sent, w1, w2, vb, sb, w1b, w2b);
        ta_mfma_gemm<<<dim3(512 + 64), dim3(256), 0, stream>>>(
            vb, w1b, b1, vmask, tmp1h, sb, w2b, smask, tmp2h, wt, wsum);
        ta_tanh_main<<<dim3(BB * (TV / 4) * 2), dim3(256), 0, stream>>>(
            tmp1h, tmp2h, wt, wsum, vmask, smask, out);
    }
}

// Round 16
// 35.410 us; speedup vs baseline: 7.9496x; 7.9496x over previous
//
#include <hip/hip_runtime.h>

#define BB 16
#define TV 256
#define TS 32
#define DD 512

typedef float    floatx4  __attribute__((ext_vector_type(4)));
typedef short    short8   __attribute__((ext_vector_type(8)));
typedef unsigned short ushort8 __attribute__((ext_vector_type(8)));

#define TANH_SCALE 2.885390082f   // 2*log2(e): tanh(y)=1-2/(exp2(2y*log2e)+1)

static __device__ __forceinline__ unsigned short f2bf(float f) {
    unsigned int u = __float_as_uint(f);
    u += 0x7FFFu + ((u >> 16) & 1u);   // RNE (inputs finite)
    return (unsigned short)(u >> 16);
}

// ---------------------------------------------------------------------------
// Pass 1: convert video/sent/w1/w2 f32 -> bf16 (measured ~1us hot).
// ---------------------------------------------------------------------------
__global__ __launch_bounds__(256) void ta_convert(
    const float* __restrict__ video, const float* __restrict__ sent,
    const float* __restrict__ w1,    const float* __restrict__ w2,
    unsigned short* __restrict__ vb, unsigned short* __restrict__ sb,
    unsigned short* __restrict__ w1b, unsigned short* __restrict__ w2b)
{
    const int NV = BB * TV * DD, NS = BB * TS * DD, NW = DD * DD;
    const int base = (blockIdx.x * 256 + threadIdx.x) * 8;
    const float* src; unsigned short* dst; int off;
    if      (base < NV)           { src = video; dst = vb;  off = base; }
    else if (base < NV + NS)      { src = sent;  dst = sb;  off = base - NV; }
    else if (base < NV + NS + NW) { src = w1;    dst = w1b; off = base - NV - NS; }
    else                          { src = w2;    dst = w2b; off = base - NV - NS - NW; }
    const float4 a = *(const float4*)(src + off);
    const float4 b = *(const float4*)(src + off + 4);
    ushort8 o;
    o[0] = f2bf(a.x); o[1] = f2bf(a.y); o[2] = f2bf(a.z); o[3] = f2bf(a.w);
    o[4] = f2bf(b.x); o[5] = f2bf(b.y); o[6] = f2bf(b.z); o[7] = f2bf(b.w);
    *(ushort8*)(dst + off) = o;
}

// ---------------------------------------------------------------------------
// Pass 2: merged bf16-MFMA NT GEMM (measured ~2.5us, unchanged from R13).
// g1: tmp1h[m][n] = bf16(exp2(clamp((val+b1[n])*vmask[m]*C)))
// g2: tmp2h [b][s>>4][n>>1][s&15][n&1] bf16 (s-half split)
// ---------------------------------------------------------------------------
__global__ __launch_bounds__(256) void ta_mfma_gemm(
    const unsigned short* __restrict__ vb, const unsigned short* __restrict__ w1b,
    const float* __restrict__ b1,          const float* __restrict__ vmask,
    unsigned short* __restrict__ tmp1h,
    const unsigned short* __restrict__ sb, const unsigned short* __restrict__ w2b,
    const float* __restrict__ smask,       unsigned short* __restrict__ tmp2h,
    const float* __restrict__ wt,          float* __restrict__ wsum)
{
    const int t = threadIdx.x;
    if (blockIdx.x == 0 && t < 64) {
        float v = 0.f;
        for (int i = t; i < DD; i += 64) v += wt[i];
        for (int off = 32; off; off >>= 1) v += __shfl_down(v, off);
        if (t == 0) wsum[0] = v;
    }
    const bool g2 = (blockIdx.x >= 512);
    const int bid = g2 ? (int)blockIdx.x - 512 : (int)blockIdx.x;
    const unsigned short* __restrict__ A = g2 ? sb    : vb;
    const unsigned short* __restrict__ W = g2 ? w2b   : w1b;
    const float* __restrict__ rm         = g2 ? smask : vmask;
    const int m0 = (g2 ? (bid & 7)  : (bid & 63)) * 64;
    const int n0 = (g2 ? (bid >> 3) : (bid >> 6)) * 64;

    __shared__ unsigned short As[2][4096];
    __shared__ unsigned short Bs[2][4096];

    const int lane = t & 63;
    const int wid  = t >> 6;
    const int wm   = wid >> 1, wn = wid & 1;
    const int lr   = lane & 15, kg = lane >> 4;

    const int r0 = t >> 3,          g0c = (t & 7) ^ (r0 & 7);
    const int r1 = (t + 256) >> 3,  g1c = (t & 7) ^ (r1 & 7);
    const unsigned short* a0p = A + (size_t)(m0 + r0) * DD + g0c * 8;
    const unsigned short* a1p = A + (size_t)(m0 + r1) * DD + g1c * 8;
    const unsigned short* w0p = W + (size_t)(n0 + r0) * DD + g0c * 8;
    const unsigned short* w1p = W + (size_t)(n0 + r1) * DD + g1c * 8;
    const int l0 = t * 8;
    const int l1 = (t + 256) * 8;

#define TA_STAGE(buf, koff) do {                                               \
    __builtin_amdgcn_global_load_lds(                                          \
        (const __attribute__((address_space(1))) void*)(a0p + (koff)),         \
        (__attribute__((address_space(3))) void*)&As[buf][l0], 16, 0, 0);      \
    __builtin_amdgcn_global_load_lds(                                          \
        (const __attribute__((address_space(1))) void*)(a1p + (koff)),         \
        (__attribute__((address_space(3))) void*)&As[buf][l1], 16, 0, 0);      \
    __builtin_amdgcn_global_load_lds(                                          \
        (const __attribute__((address_space(1))) void*)(w0p + (koff)),         \
        (__attribute__((address_space(3))) void*)&Bs[buf][l0], 16, 0, 0);      \
    __builtin_amdgcn_global_load_lds(                                          \
        (const __attribute__((address_space(1))) void*)(w1p + (koff)),         \
        (__attribute__((address_space(3))) void*)&Bs[buf][l1], 16, 0, 0);      \
  } while (0)

    floatx4 acc[2][2] = {};
    const int ml0 = wm * 32 + lr, ml1 = ml0 + 16;
    const int nl0 = wn * 32 + lr, nl1 = nl0 + 16;
    const int sa0 = ml0 * 64, sa1 = ml1 * 64;
    const int sb0 = nl0 * 64, sb1 = nl1 * 64;
    const int xa = ml0 & 7, xb = nl0 & 7;

    TA_STAGE(0, 0);
    __syncthreads();
    int cur = 0;
    for (int step = 0; step < 8; ++step) {
        if (step < 7) TA_STAGE(cur ^ 1, (step + 1) * 64);
#pragma unroll
        for (int kk = 0; kk < 2; ++kk) {
            const int kc = kk * 4 + kg;
            short8 a0 = *(const short8*)&As[cur][sa0 + ((kc ^ xa) << 3)];
            short8 a1 = *(const short8*)&As[cur][sa1 + ((kc ^ xa) << 3)];
            short8 b0 = *(const short8*)&Bs[cur][sb0 + ((kc ^ xb) << 3)];
            short8 b1 = *(const short8*)&Bs[cur][sb1 + ((kc ^ xb) << 3)];
            acc[0][0] = __builtin_amdgcn_mfma_f32_16x16x32_bf16(a0, b0, acc[0][0], 0, 0, 0);
            acc[0][1] = __builtin_amdgcn_mfma_f32_16x16x32_bf16(a0, b1, acc[0][1], 0, 0, 0);
            acc[1][0] = __builtin_amdgcn_mfma_f32_16x16x32_bf16(a1, b0, acc[1][0], 0, 0, 0);
            acc[1][1] = __builtin_amdgcn_mfma_f32_16x16x32_bf16(a1, b1, acc[1][1], 0, 0, 0);
        }
        __syncthreads();
        cur ^= 1;
    }
#undef TA_STAGE

#pragma unroll
    for (int fm = 0; fm < 2; ++fm)
#pragma unroll
        for (int fn = 0; fn < 2; ++fn)
#pragma unroll
            for (int r = 0; r < 4; ++r) {
                const int m = m0 + wm * 32 + fm * 16 + kg * 4 + r;
                const int n = n0 + wn * 32 + fn * 16 + lr;
                const float mk = rm[m] * TANH_SCALE;
                float z = g2 ? (acc[fm][fn][r] * mk)
                             : (acc[fm][fn][r] + b1[n]) * mk;
                z = fminf(fmaxf(z, -30.f), 30.f);
                const float e = __builtin_amdgcn_exp2f(z);
                if (!g2) {
                    tmp1h[(size_t)m * DD + n] = f2bf(e);
                } else {
                    const int bb = m >> 5, ss = m & 31;
                    tmp2h[(size_t)bb * 16384 + (size_t)(ss >> 4) * 8192
                          + (size_t)(n >> 1) * 32 + (ss & 15) * 2 + (n & 1)] = f2bf(e);
                }
            }
}

// ---------------------------------------------------------------------------
// Pass 3: tanh reduction, LOW-DUPLICATION tiling: 16 v per block.
// Grid 512 = b(16) x sh(2) x vt(16); block 256 = 16s x 4vi x 4q.
// Thread covers 4 v rows {vi, vi+4, vi+8, vi+12} over a 128-d slice (q).
// Staged bytes drop 40MB -> 16MB grid-wide (E2 dup 64x -> 16x), attacking
// the measured ~15us stage-convoy (R12: VALUBusy 80%, idle = stage wait).
// LDS: E2 16KB + E1 16x520 ushorts (pad->conflict-free b128) + part 4KB.
// ---------------------------------------------------------------------------
__global__ __launch_bounds__(256) void ta_tanh_main(
    const unsigned short* __restrict__ tmp1h, // [B*TV][D] bf16 = E1
    const unsigned short* __restrict__ tmp2h, // [B][2][D/2][16][2] bf16 = E2
    const float* __restrict__ wt,             // [D]
    const float* __restrict__ wsum,           // [1]
    const float* __restrict__ vmask,          // [B*TV]
    const float* __restrict__ smask,          // [B*TS]
    float* __restrict__ out)                  // [B][TV][TS]
{
    __shared__ unsigned int   e2u[4096];      // 16 KB: [d2 256][s16] pairs
    __shared__ unsigned short e1u[16 * 520];  // 16.25 KB (16B row pad)
    __shared__ float part[1024];              // 4 KB: [v16][s16][q4]

    const int t   = threadIdx.x;
    const int bid = blockIdx.x;
    const int b   = bid >> 5;                 // 16 batches
    const int sh  = (bid >> 4) & 1;           // s-half
    const int v0  = (bid & 15) << 4;          // 16 v-tiles of 16

    {   // async stage: E2 16KB (4x16B/thread) + E1 16KB (4x16B/thread)
        const unsigned short* e2src = tmp2h + (size_t)b * 16384 + sh * 8192 + t * 8;
#pragma unroll
        for (int i = 0; i < 4; ++i) {
            __builtin_amdgcn_global_load_lds(
                (const __attribute__((address_space(1))) void*)(e2src + i * 2048),
                (__attribute__((address_space(3))) void*)&e2u[t * 4 + i * 1024], 16, 0, 0);
        }
#pragma unroll
        for (int i = 0; i < 4; ++i) {
            const int c = t + 256 * i;        // 1024 chunks = 16 rows x 64
            const int row = c >> 6, col = (c & 63) * 8;   // row wave-uniform
            __builtin_amdgcn_global_load_lds(
                (const __attribute__((address_space(1))) void*)
                    (tmp1h + (size_t)(b * TV + v0 + row) * DD + col),
                (__attribute__((address_space(3))) void*)&e1u[row * 520 + col], 16, 0, 0);
        }
    }
    __syncthreads();

    const int s  = t & 15;
    const int vi = (t >> 4) & 3;
    const int q  = t >> 6;                    // 0..3, 128-d slice, wave-uniform

    const float* __restrict__ wtp = wt + q * 128;
    const int d2b = q * 64;                   // base d2 for this slice

    floatx4 acc0 = {0.f, 0.f, 0.f, 0.f};     // v = vi
    floatx4 acc1 = {0.f, 0.f, 0.f, 0.f};     // v = vi+4
    floatx4 acc2 = {0.f, 0.f, 0.f, 0.f};     // v = vi+8
    floatx4 acc3 = {0.f, 0.f, 0.f, 0.f};     // v = vi+12
#pragma unroll 4
    for (int i = 0; i < 16; ++i) {
        const int ub = (d2b + i * 4) * 16 + s;
        const unsigned u0 = e2u[ub];          // 16 lanes consecutive + 4-way
        const unsigned u1 = e2u[ub + 16];     //   broadcast -> conflict-free
        const unsigned u2 = e2u[ub + 32];
        const unsigned u3 = e2u[ub + 48];
        const int e1off = q * 128 + i * 8;
        ushort8 r0 = *(const ushort8*)(e1u + (vi     ) * 520 + e1off);
        ushort8 r1 = *(const ushort8*)(e1u + (vi +  4) * 520 + e1off);
        ushort8 r2 = *(const ushort8*)(e1u + (vi +  8) * 520 + e1off);
        ushort8 r3 = *(const ushort8*)(e1u + (vi + 12) * 520 + e1off);
        floatx4 wa = *(const floatx4*)(wtp + i * 8);
        floatx4 wb = *(const floatx4*)(wtp + i * 8 + 4);
        const float e2v[8] = {
            __uint_as_float(u0 << 16), __uint_as_float(u0 & 0xffff0000u),
            __uint_as_float(u1 << 16), __uint_as_float(u1 & 0xffff0000u),
            __uint_as_float(u2 << 16), __uint_as_float(u2 & 0xffff0000u),
            __uint_as_float(u3 << 16), __uint_as_float(u3 & 0xffff0000u)
        };
#pragma unroll
        for (int j = 0; j < 4; ++j) {
            const float x0 = __uint_as_float((unsigned)r0[j] << 16);
            const float x1 = __uint_as_float((unsigned)r1[j] << 16);
            const float x2 = __uint_as_float((unsigned)r2[j] << 16);
            const float x3 = __uint_as_float((unsigned)r3[j] << 16);
            acc0[j] = fmaf(wa[j], __builtin_amdgcn_rcpf(fmaf(x0, e2v[j], 1.f)), acc0[j]);
            acc1[j] = fmaf(wa[j], __builtin_amdgcn_rcpf(fmaf(x1, e2v[j], 1.f)), acc1[j]);
            acc2[j] = fmaf(wa[j], __builtin_amdgcn_rcpf(fmaf(x2, e2v[j], 1.f)), acc2[j]);
            acc3[j] = fmaf(wa[j], __builtin_amdgcn_rcpf(fmaf(x3, e2v[j], 1.f)), acc3[j]);
        }
#pragma unroll
        for (int j = 0; j < 4; ++j) {
            const float x0 = __uint_as_float((unsigned)r0[j + 4] << 16);
            const float x1 = __uint_as_float((unsigned)r1[j + 4] << 16);
            const float x2 = __uint_as_float((unsigned)r2[j + 4] << 16);
            const float x3 = __uint_as_float((unsigned)r3[j + 4] << 16);
            acc0[j] = fmaf(wb[j], __builtin_amdgcn_rcpf(fmaf(x0, e2v[j + 4], 1.f)), acc0[j]);
            acc1[j] = fmaf(wb[j], __builtin_amdgcn_rcpf(fmaf(x1, e2v[j + 4], 1.f)), acc1[j]);
            acc2[j] = fmaf(wb[j], __builtin_amdgcn_rcpf(fmaf(x2, e2v[j + 4], 1.f)), acc2[j]);
            acc3[j] = fmaf(wb[j], __builtin_amdgcn_rcpf(fmaf(x3, e2v[j + 4], 1.f)), acc3[j]);
        }
    }

    part[(vi     ) * 64 + s * 4 + q] = (acc0[0] + acc0[1]) + (acc0[2] + acc0[3]);
    part[(vi +  4) * 64 + s * 4 + q] = (acc1[0] + acc1[1]) + (acc1[2] + acc1[3]);
    part[(vi +  8) * 64 + s * 4 + q] = (acc2[0] + acc2[1]) + (acc2[2] + acc2[3]);
    part[(vi + 12) * 64 + s * 4 + q] = (acc3[0] + acc3[1]) + (acc3[2] + acc3[3]);
    __syncthreads();

    {   // 256 threads = 16 v x 16 s outputs
        const int vrow = t >> 4, s2 = t & 15;
        const floatx4 p = *(const floatx4*)&part[vrow * 64 + s2 * 4];
        const float sum = (p[0] + p[1]) + (p[2] + p[3]);
        const int v  = v0 + vrow;
        const int sg = sh * 16 + s2;
        const float pm = vmask[b * TV + v] * smask[b * TS + sg];
        out[((size_t)b * TV + v) * TS + sg] = pm * (wsum[0] - 2.f * sum);
    }
}

// ---------------------------------------------------------------------------
extern "C" void kernel_launch(void* const* d_in, const int* in_sizes, int n_in,
                              void* d_out, int out_size, void* d_ws, size_t ws_size,
                              hipStream_t stream)
{
    const float* video = (const float*)d_in[0];
    const float* vmask = (const float*)d_in[1];
    const float* sent  = (const float*)d_in[2];
    const float* smask = (const float*)d_in[3];
    const float* w1    = (const float*)d_in[4];
    const float* b1    = (const float*)d_in[5];
    const float* w2    = (const float*)d_in[6];
    const float* wt    = (const float*)d_in[7];
    float* out = (float*)d_out;

    const size_t NV = (size_t)BB * TV * DD, NS = (size_t)BB * TS * DD, NW = (size_t)DD * DD;

    unsigned short* tmp1h = (unsigned short*)d_ws;   // 4 MB bf16 (E1)
    unsigned short* tmp2h = tmp1h + NV;              // 512 KB bf16 (E2)
    unsigned short* vb    = tmp2h + NS;
    unsigned short* sb    = vb + NV;
    unsigned short* w1b   = sb + NS;
    unsigned short* w2b   = w1b + NW;
    float* wsum           = (float*)(w2b + NW);

    const int total8 = (int)((NV + NS + 2 * NW) / 8);
    ta_convert<<<dim3(total8 / 256), dim3(256), 0, stream>>>(
        video, sent, w1, w2, vb, sb, w1b, w2b);
    ta_mfma_gemm<<<dim3(512 + 64), dim3(256), 0, stream>>>(
        vb, w1b, b1, vmask, tmp1h, sb, w2b, smask, tmp2h, wt, wsum);
    ta_tanh_main<<<dim3(512), dim3(256), 0, stream>>>(
        tmp1h, tmp2h, wt, wsum, vmask, smask, out);
}